// Round 12
// baseline (343.227 us; speedup 1.0000x reference)
//
#include <hip/hip_runtime.h>
#include <math.h>

#define T_STEPS 168
#define INP     19
#define HID     64
#define ROWS    16
#define NTH     512
#define HSTH    72    // h row stride (f16): 144 B, 16B-aligned
#define XSTH    40    // x row stride (f16): 80 B

typedef _Float16 half8   __attribute__((ext_vector_type(8)));
typedef float    floatx4 __attribute__((ext_vector_type(4)));

__device__ __forceinline__ float fast_sigmoid(float x) {
    return __builtin_amdgcn_rcpf(1.0f + __expf(-x));
}
__device__ __forceinline__ float fast_tanh(float x) {
    return 1.0f - 2.0f * __builtin_amdgcn_rcpf(1.0f + __expf(2.0f * x));
}

// r8 compute structure, but the per-iter __syncthreads is replaced by a
// producer-consumer spin-flag protocol (r11 falsified the vmcnt-drain theory;
// the residual idle is barrier phase-locking: all waves burst ds_read, then
// all burst trans, pipes used serially). Flags W[w] = iterations completed by
// wave w, in LDS (broadcast spin-reads are conflict-free).
//   layer1 wave @ iter t:  spin W[0..3]>=t  (h1(t-1), x(t) from l1 peers)
//                          ...compute... stage x ... spin W[4..7]>=t (WAR on
//                          h1 buffer t&1, last read by layer2 @ t-1) -> write
//   layer2 wave @ iter t:  spin W[0..7]>=t -> compute -> write
//   publish: s_waitcnt lgkmcnt(0); W[w]=t+1  (writes visible before flag)
// Deadlock-free: finishing iter t needs the OTHER group at >= t (= finished
// t-1), never equal-iter mutual wait. Groups can slide ~1 iter apart.
// x staging moved into layer1 waves (wave uq stages rows uq*4..+3) so x needs
// no extra flag: covered by W[0..3].
__global__ __launch_bounds__(NTH) __attribute__((amdgpu_waves_per_eu(2, 2)))
void lstm2_mfma8_kernel(const float* __restrict__ x,
                        const float* __restrict__ Wih0, const float* __restrict__ Whh0,
                        const float* __restrict__ bih0, const float* __restrict__ bhh0,
                        const float* __restrict__ Wih1, const float* __restrict__ Whh1,
                        const float* __restrict__ bih1, const float* __restrict__ bhh1,
                        const float* __restrict__ Wfc,  const float* __restrict__ bfc,
                        float* __restrict__ out)
{
    __shared__ __align__(16) _Float16 xf [2][ROWS][XSTH];   // cols 19.. stay 0
    __shared__ __align__(16) _Float16 h1f[2][ROWS][HSTH];
    __shared__ __align__(16) _Float16 h2f[2][ROWS][HSTH];
    __shared__ float hout[ROWS][HID];
    __shared__ int   wflags[8 * 8];    // W[w] at wflags[w*8] (bank-spread)

    const int tid  = threadIdx.x;
    const int b0   = blockIdx.x * ROWS;
    const int wv   = tid >> 6;
    const int lane = tid & 63;
    const int quad = lane >> 4;
    const int l16  = lane & 15;
    const int kq   = quad * 8;
    const int lay  = wv >> 2;          // 0: layer1(t), 1: layer2(t-1)
    const int uq   = wv & 3;
    const int u    = uq * 16 + l16;

    // ---- B-fragments (weights, f16) + bias: loaded ONCE (r8-identical) ----
    half8 bfr[4][4];
    float bz[4];
#pragma unroll
    for (int gi = 0; gi < 4; ++gi) {
        const int gr = gi * 64 + u;
        if (lay == 0) {
            const float* wr = Wih0 + gr * INP;
#pragma unroll
            for (int e = 0; e < 8; ++e) {
                const int k = kq + e;
                bfr[gi][0][e] = (k < INP) ? (_Float16)wr[k] : (_Float16)0.0f;
            }
            const float* hr = Whh0 + gr * HID;
#pragma unroll
            for (int e = 0; e < 8; ++e) {
                bfr[gi][1][e] = (_Float16)hr[kq + e];
                bfr[gi][2][e] = (_Float16)hr[32 + kq + e];
            }
            bfr[gi][3] = bfr[gi][2];
            bz[gi] = bih0[gr] + bhh0[gr];
        } else {
            const float* ir = Wih1 + gr * HID;
            const float* hr = Whh1 + gr * HID;
#pragma unroll
            for (int e = 0; e < 8; ++e) {
                bfr[gi][0][e] = (_Float16)ir[kq + e];
                bfr[gi][1][e] = (_Float16)ir[32 + kq + e];
                bfr[gi][2][e] = (_Float16)hr[kq + e];
                bfr[gi][3][e] = (_Float16)hr[32 + kq + e];
            }
            bz[gi] = bih1[gr] + bhh1[gr];
        }
    }

    float cst[4] = {0.f, 0.f, 0.f, 0.f};

    // ---- x staging: layer1 wave uq stages rows uq*4..+3 (76 elems/wave) ----
    bool stA = false, stB = false;
    int rA = 0, cA = 0, rB = 0, cB = 0;
    const float *pA = nullptr, *pB = nullptr;
    if (lay == 0) {
        int e = lane;
        if (e < 4 * INP) {
            rA = uq * 4 + e / INP; cA = e % INP; stA = true;
            pA = x + ((size_t)(b0 + rA) * T_STEPS) * INP + cA;
        }
        e = lane + 64;
        if (e < 4 * INP) {
            rB = uq * 4 + e / INP; cB = e % INP; stB = true;
            pB = x + ((size_t)(b0 + rB) * T_STEPS) * INP + cB;
        }
    }

    // ---- init LDS ----
    for (int e = tid; e < 2 * ROWS * XSTH; e += NTH) ((_Float16*)xf)[e] = (_Float16)0.f;
    for (int e = tid; e < 2 * ROWS * HSTH; e += NTH) {
        ((_Float16*)h1f)[e] = (_Float16)0.f;
        ((_Float16*)h2f)[e] = (_Float16)0.f;
    }
    if (tid < 8) wflags[tid * 8] = 0;
    __syncthreads();
    // pre-stage x(0); preload x(1), x(2) into the register pipeline
    float xA1 = 0.f, xA2 = 0.f, xB1 = 0.f, xB2 = 0.f;
    if (stA) { xf[0][rA][cA] = (_Float16)pA[0]; xA1 = pA[INP]; xA2 = pA[2 * (size_t)INP]; }
    if (stB) { xf[0][rB][cB] = (_Float16)pB[0]; xB1 = pB[INP]; xB2 = pB[2 * (size_t)INP]; }
    __syncthreads();

    volatile int* wf = (volatile int*)wflags;

    for (int t = 0; t <= T_STEPS; ++t) {
        // ---- acquire: inputs of this iter are published ----
        if (lay == 0) {
            while (wf[0] < t || wf[8] < t || wf[16] < t || wf[24] < t)
                __builtin_amdgcn_s_sleep(1);
        } else {
            while (wf[0]  < t || wf[8]  < t || wf[16] < t || wf[24] < t ||
                   wf[32] < t || wf[40] < t || wf[48] < t || wf[56] < t)
                __builtin_amdgcn_s_sleep(1);
        }
        asm volatile("" ::: "memory");

        const bool act = (lay == 0) ? (t < T_STEPS) : (t >= 1);
        float hv[4];
        if (act) {
            floatx4 acc[4];
#pragma unroll
            for (int gi = 0; gi < 4; ++gi)
                acc[gi] = (floatx4){bz[gi], bz[gi], bz[gi], bz[gi]};
            if (lay == 0) {
                const half8 ax = *(const half8*)&xf [t & 1][l16][kq];
                const half8 a0 = *(const half8*)&h1f[(t + 1) & 1][l16][kq];
                const half8 a1 = *(const half8*)&h1f[(t + 1) & 1][l16][32 + kq];
#pragma unroll
                for (int gi = 0; gi < 4; ++gi) {
                    acc[gi] = __builtin_amdgcn_mfma_f32_16x16x32_f16(ax, bfr[gi][0], acc[gi], 0, 0, 0);
                    acc[gi] = __builtin_amdgcn_mfma_f32_16x16x32_f16(a0, bfr[gi][1], acc[gi], 0, 0, 0);
                    acc[gi] = __builtin_amdgcn_mfma_f32_16x16x32_f16(a1, bfr[gi][2], acc[gi], 0, 0, 0);
                }
            } else {
                const half8 p0 = *(const half8*)&h1f[(t + 1) & 1][l16][kq];
                const half8 p1 = *(const half8*)&h1f[(t + 1) & 1][l16][32 + kq];
                const half8 q0 = *(const half8*)&h2f[t & 1][l16][kq];
                const half8 q1 = *(const half8*)&h2f[t & 1][l16][32 + kq];
#pragma unroll
                for (int gi = 0; gi < 4; ++gi) {
                    acc[gi] = __builtin_amdgcn_mfma_f32_16x16x32_f16(p0, bfr[gi][0], acc[gi], 0, 0, 0);
                    acc[gi] = __builtin_amdgcn_mfma_f32_16x16x32_f16(p1, bfr[gi][1], acc[gi], 0, 0, 0);
                    acc[gi] = __builtin_amdgcn_mfma_f32_16x16x32_f16(q0, bfr[gi][2], acc[gi], 0, 0, 0);
                    acc[gi] = __builtin_amdgcn_mfma_f32_16x16x32_f16(q1, bfr[gi][3], acc[gi], 0, 0, 0);
                }
            }
#pragma unroll
            for (int rg = 0; rg < 4; ++rg) {
                const float ig = fast_sigmoid(acc[0][rg]);
                const float fg = fast_sigmoid(acc[1][rg]);
                const float gg = fast_tanh(acc[2][rg]);
                const float og = fast_sigmoid(acc[3][rg]);
                cst[rg] = fg * cst[rg] + ig * gg;
                hv[rg]  = og * fast_tanh(cst[rg]);
            }
        }

        if (lay == 0) {
            // stage x(t+1) (buffer (t+1)&1: peers' x(t-1) reads done, W>=t);
            // prefetch x(t+3) -- latency overlaps the WAR spin below
            float nA = 0.f, nB = 0.f;
            if (stA) {
                if (t + 1 < T_STEPS) xf[(t + 1) & 1][rA][cA] = (_Float16)xA1;
                const int tn = (t + 3 < T_STEPS) ? (t + 3) : (T_STEPS - 1);
                nA = pA[(size_t)tn * INP];
            }
            if (stB) {
                if (t + 1 < T_STEPS) xf[(t + 1) & 1][rB][cB] = (_Float16)xB1;
                const int tn = (t + 3 < T_STEPS) ? (t + 3) : (T_STEPS - 1);
                nB = pB[(size_t)tn * INP];
            }
            // WAR: h1 buffer t&1 was last read by layer2 at iter t-1
            while (wf[32] < t || wf[40] < t || wf[48] < t || wf[56] < t)
                __builtin_amdgcn_s_sleep(1);
            asm volatile("" ::: "memory");
            if (act) {
#pragma unroll
                for (int rg = 0; rg < 4; ++rg)
                    h1f[t & 1][quad * 4 + rg][u] = (_Float16)hv[rg];   // h1(t)
            }
            xA1 = xA2; xA2 = nA; xB1 = xB2; xB2 = nB;
        } else {
            if (act) {
#pragma unroll
                for (int rg = 0; rg < 4; ++rg) {
                    const int row = quad * 4 + rg;
                    h2f[(t + 1) & 1][row][u] = (_Float16)hv[rg];       // h2(t-1)
                    if (t == T_STEPS) hout[row][u] = hv[rg];
                }
            }
        }

        // ---- publish: my LDS writes drained, then bump my flag ----
        asm volatile("s_waitcnt lgkmcnt(0)" ::: "memory");
        if (lane == 0) wf[wv * 8] = t + 1;
    }
    __syncthreads();

    // ---- FC epilogue: out[b] = h2(T-1)[b,:] . Wfc + bfc ----
    if (tid < ROWS) {
        float a = bfc[0];
        const float* hr = hout[tid];
#pragma unroll
        for (int k = 0; k < HID; ++k)
            a = fmaf(hr[k], Wfc[k], a);
        out[b0 + tid] = a;
    }
}

extern "C" void kernel_launch(void* const* d_in, const int* in_sizes, int n_in,
                              void* d_out, int out_size, void* d_ws, size_t ws_size,
                              hipStream_t stream) {
    const float* x    = (const float*)d_in[0];
    const float* Wih0 = (const float*)d_in[1];
    const float* Whh0 = (const float*)d_in[2];
    const float* bih0 = (const float*)d_in[3];
    const float* bhh0 = (const float*)d_in[4];
    const float* Wih1 = (const float*)d_in[5];
    const float* Whh1 = (const float*)d_in[6];
    const float* bih1 = (const float*)d_in[7];
    const float* bhh1 = (const float*)d_in[8];
    const float* Wfc  = (const float*)d_in[9];
    const float* bfc  = (const float*)d_in[10];
    float* out = (float*)d_out;

    const int B = in_sizes[0] / (T_STEPS * INP);   // 4096
    const int grid = B / ROWS;                     // 256 workgroups, 1 per CU

    lstm2_mfma8_kernel<<<dim3(grid), dim3(NTH), 0, stream>>>(
        x, Wih0, Whh0, bih0, bhh0, Wih1, Whh1, bih1, bhh1, Wfc, bfc, out);
}

// Round 13
// 253.497 us; speedup vs baseline: 1.3540x; 1.3540x over previous
//
#include <hip/hip_runtime.h>
#include <math.h>

#define T_STEPS 168
#define INP     19
#define HID     64
#define ROWS    16
#define NTH     512
#define HSTH    72    // h row stride (f16): 144 B, 16B-aligned
#define XSTH    40    // x row stride (f16): 80 B

typedef _Float16 half8   __attribute__((ext_vector_type(8)));
typedef float    floatx4 __attribute__((ext_vector_type(4)));

__device__ __forceinline__ float fast_sigmoid(float x) {
    return __builtin_amdgcn_rcpf(1.0f + __expf(-x));
}
__device__ __forceinline__ float fast_tanh(float x) {
    return 1.0f - 2.0f * __builtin_amdgcn_rcpf(1.0f + __expf(2.0f * x));
}

// FINAL (r8 structure, best measured: 186 us dispatch / 253 us bench):
//  - 8 waves: 4 compute layer1(t), 4 compute layer2(t-1) (software skew).
//  - Weights live in VGPRs as MFMA B-fragments for the whole kernel;
//    per-wave all-4-gates tiling puts z directly in the C-layout so
//    activation + cell state never leave registers.
//  - xf/h1f/h2f double-buffered -> single __syncthreads per timestep
//    (the dataflow minimum: h is all-to-all across waves every step).
//  - x global load software-pipelined 2 iters ahead in registers.
// Measured-negative alternatives (do not revisit): ROWS=8 2-blocks/CU (r9,
// +63% busy), gate-split 16 waves (r10, +76% busy), lgkm-only barrier (r11,
// neutral), spin-flag producer/consumer (r12, +60% wall). Residual ~40% idle
// is the per-step latency chain (barrier + ds_read + MFMA + serial
// activation) -- structural at 1 sync/timestep.
__global__ __launch_bounds__(NTH) __attribute__((amdgpu_waves_per_eu(2, 2)))
void lstm2_mfma3_kernel(const float* __restrict__ x,
                        const float* __restrict__ Wih0, const float* __restrict__ Whh0,
                        const float* __restrict__ bih0, const float* __restrict__ bhh0,
                        const float* __restrict__ Wih1, const float* __restrict__ Whh1,
                        const float* __restrict__ bih1, const float* __restrict__ bhh1,
                        const float* __restrict__ Wfc,  const float* __restrict__ bfc,
                        float* __restrict__ out)
{
    __shared__ __align__(16) _Float16 xf [2][ROWS][XSTH];   // cols 19.. stay 0
    __shared__ __align__(16) _Float16 h1f[2][ROWS][HSTH];
    __shared__ __align__(16) _Float16 h2f[2][ROWS][HSTH];
    __shared__ float hout[ROWS][HID];                       // fp32 h2(T-1) for FC

    const int tid  = threadIdx.x;
    const int b0   = blockIdx.x * ROWS;
    const int wv   = tid >> 6;
    const int lane = tid & 63;
    const int quad = lane >> 4;
    const int l16  = lane & 15;
    const int kq   = quad * 8;         // k-offset inside a 32-wide K-tile
    const int lay  = wv >> 2;          // 0: layer1(t), 1: layer2(t-1)
    const int uq   = wv & 3;           // unit quarter
    const int u    = uq * 16 + l16;    // my unit column

    // ---- B-fragments (weights, f16) + bias: loaded ONCE ----
    // B[k][n]: n = lane&15, k = quad*8 + e
    half8 bfr[4][4];
    float bz[4];
#pragma unroll
    for (int gi = 0; gi < 4; ++gi) {
        const int gr = gi * 64 + u;
        if (lay == 0) {
            const float* wr = Wih0 + gr * INP;
#pragma unroll
            for (int e = 0; e < 8; ++e) {
                const int k = kq + e;
                bfr[gi][0][e] = (k < INP) ? (_Float16)wr[k] : (_Float16)0.0f;
            }
            const float* hr = Whh0 + gr * HID;
#pragma unroll
            for (int e = 0; e < 8; ++e) {
                bfr[gi][1][e] = (_Float16)hr[kq + e];
                bfr[gi][2][e] = (_Float16)hr[32 + kq + e];
            }
            bfr[gi][3] = bfr[gi][2];   // unused on this path
            bz[gi] = bih0[gr] + bhh0[gr];
        } else {
            const float* ir = Wih1 + gr * HID;
            const float* hr = Whh1 + gr * HID;
#pragma unroll
            for (int e = 0; e < 8; ++e) {
                bfr[gi][0][e] = (_Float16)ir[kq + e];
                bfr[gi][1][e] = (_Float16)ir[32 + kq + e];
                bfr[gi][2][e] = (_Float16)hr[kq + e];
                bfr[gi][3][e] = (_Float16)hr[32 + kq + e];
            }
            bz[gi] = bih1[gr] + bhh1[gr];
        }
    }

    // cell state: rows quad*4..+3 of unit u
    float cst[4] = {0.f, 0.f, 0.f, 0.f};

    // ---- x staging constants (threads 0..303 stage one element/iter) ----
    int srr = 0, sii = 0;
    const float* xsrc = nullptr;
    if (tid < ROWS * INP) {
        srr = tid / INP; sii = tid - srr * INP;
        xsrc = x + ((size_t)(b0 + srr) * T_STEPS) * INP + sii;
    }

    // ---- init LDS (both buffers zero; pad cols stay zero forever) ----
    for (int e = tid; e < 2 * ROWS * XSTH; e += NTH) ((_Float16*)xf)[e] = (_Float16)0.f;
    for (int e = tid; e < 2 * ROWS * HSTH; e += NTH) {
        ((_Float16*)h1f)[e] = (_Float16)0.f;
        ((_Float16*)h2f)[e] = (_Float16)0.f;
    }
    __syncthreads();
    float xreg = 0.f;
    if (xsrc) {
        xf[0][srr][sii] = (_Float16)xsrc[0];   // stage x(0) directly
        xreg = xsrc[INP];                      // x(1) held in register
    }
    __syncthreads();

    for (int t = 0; t <= T_STEPS; ++t) {
        // ---- issue x(t+2) load FIRST: latency overlaps the whole compute ----
        float xnew = 0.f;
        if (xsrc) {
            const int tn = (t + 2 < T_STEPS) ? (t + 2) : (T_STEPS - 1);
            xnew = xsrc[(size_t)tn * INP];
        }
        // ---- stage x(t+1) from the register loaded last iter (no vm wait) ----
        if (xsrc && (t + 1) < T_STEPS)
            xf[(t + 1) & 1][srr][sii] = (_Float16)xreg;

        const bool act = (lay == 0) ? (t < T_STEPS) : (t >= 1);
        if (act) {
            floatx4 acc[4];
#pragma unroll
            for (int gi = 0; gi < 4; ++gi)
                acc[gi] = (floatx4){bz[gi], bz[gi], bz[gi], bz[gi]};
            if (lay == 0) {
                // A[m=lane&15][k=quad*8+e]
                const half8 ax = *(const half8*)&xf [t & 1][l16][kq];
                const half8 a0 = *(const half8*)&h1f[(t + 1) & 1][l16][kq];
                const half8 a1 = *(const half8*)&h1f[(t + 1) & 1][l16][32 + kq];
#pragma unroll
                for (int gi = 0; gi < 4; ++gi) {
                    acc[gi] = __builtin_amdgcn_mfma_f32_16x16x32_f16(ax, bfr[gi][0], acc[gi], 0, 0, 0);
                    acc[gi] = __builtin_amdgcn_mfma_f32_16x16x32_f16(a0, bfr[gi][1], acc[gi], 0, 0, 0);
                    acc[gi] = __builtin_amdgcn_mfma_f32_16x16x32_f16(a1, bfr[gi][2], acc[gi], 0, 0, 0);
                }
            } else {
                const half8 p0 = *(const half8*)&h1f[(t + 1) & 1][l16][kq];
                const half8 p1 = *(const half8*)&h1f[(t + 1) & 1][l16][32 + kq];
                const half8 q0 = *(const half8*)&h2f[t & 1][l16][kq];
                const half8 q1 = *(const half8*)&h2f[t & 1][l16][32 + kq];
#pragma unroll
                for (int gi = 0; gi < 4; ++gi) {
                    acc[gi] = __builtin_amdgcn_mfma_f32_16x16x32_f16(p0, bfr[gi][0], acc[gi], 0, 0, 0);
                    acc[gi] = __builtin_amdgcn_mfma_f32_16x16x32_f16(p1, bfr[gi][1], acc[gi], 0, 0, 0);
                    acc[gi] = __builtin_amdgcn_mfma_f32_16x16x32_f16(q0, bfr[gi][2], acc[gi], 0, 0, 0);
                    acc[gi] = __builtin_amdgcn_mfma_f32_16x16x32_f16(q1, bfr[gi][3], acc[gi], 0, 0, 0);
                }
            }
            // activations in C-layout: lane owns cells (row=quad*4+rg, u)
#pragma unroll
            for (int rg = 0; rg < 4; ++rg) {
                const float ig = fast_sigmoid(acc[0][rg]);
                const float fg = fast_sigmoid(acc[1][rg]);
                const float gg = fast_tanh(acc[2][rg]);
                const float og = fast_sigmoid(acc[3][rg]);
                cst[rg] = fg * cst[rg] + ig * gg;
                const float hv = og * fast_tanh(cst[rg]);
                const int row = quad * 4 + rg;
                if (lay == 0) {
                    h1f[t & 1][row][u] = (_Float16)hv;              // h1(t)
                } else {
                    h2f[(t + 1) & 1][row][u] = (_Float16)hv;        // h2(t-1)
                    if (t == T_STEPS) hout[row][u] = hv;            // fp32 for FC
                }
            }
        }
        xreg = xnew;       // vm wait lands here, after all compute
        __syncthreads();   // single barrier: iter-t writes visible to iter t+1
    }

    // ---- FC epilogue: out[b] = h2(T-1)[b,:] . Wfc + bfc ----
    if (tid < ROWS) {
        float a = bfc[0];
        const float* hr = hout[tid];
#pragma unroll
        for (int k = 0; k < HID; ++k)
            a = fmaf(hr[k], Wfc[k], a);
        out[b0 + tid] = a;
    }
}

extern "C" void kernel_launch(void* const* d_in, const int* in_sizes, int n_in,
                              void* d_out, int out_size, void* d_ws, size_t ws_size,
                              hipStream_t stream) {
    const float* x    = (const float*)d_in[0];
    const float* Wih0 = (const float*)d_in[1];
    const float* Whh0 = (const float*)d_in[2];
    const float* bih0 = (const float*)d_in[3];
    const float* bhh0 = (const float*)d_in[4];
    const float* Wih1 = (const float*)d_in[5];
    const float* Whh1 = (const float*)d_in[6];
    const float* bih1 = (const float*)d_in[7];
    const float* bhh1 = (const float*)d_in[8];
    const float* Wfc  = (const float*)d_in[9];
    const float* bfc  = (const float*)d_in[10];
    float* out = (float*)d_out;

    const int B = in_sizes[0] / (T_STEPS * INP);   // 4096
    const int grid = B / ROWS;                     // 256 workgroups, 1 per CU

    lstm2_mfma3_kernel<<<dim3(grid), dim3(NTH), 0, stream>>>(
        x, Wih0, Whh0, bih0, bhh0, Wih1, Whh1, bih1, bhh1, Wfc, bfc, out);
}